// Round 5
// baseline (261.139 us; speedup 1.0000x reference)
//
#include <hip/hip_runtime.h>

// OrthogonalLayer2D via Cholesky-QR (== classical Gram-Schmidt).
// x reshaped (N=8, MC=4096, D=1024). Per mc: G=VV^T (8x8), L=chol(G),
// B = L^{-1} V, rows scaled by 1/L[i][i]; degenerate pivot -> 0 (NaN->0 rule).
//
// R5 structure: 1024 blocks x 4 mc each (grid-stride), software-pipelined:
// prefetch next mc's vectors into a ping-pong register buffer while computing
// and storing the current one -> reads of iter k+1 overlap compute+stores of
// iter k (counted vmcnt keeps them in flight). Attacks the R1-R4 plateau
// (whole-grid phase lockstep: burst-load, stall, burst-store, ~100us).

#define MC    4096
#define DIM   1024
#define NV    8
#define TPB   256
#define NBLK  1024
#define ITERS 4            // MC / NBLK
#define E     4            // elems per thread (one float4 per vector)
#define IDX(i,j) ((i)*((i)+1)/2+(j))   // packed lower-tri, i >= j

typedef float f32x4 __attribute__((ext_vector_type(4)));

// one step of the gfx9 DPP wave-sum ladder
template <int CTRL, int ROWM>
__device__ __forceinline__ float dpp_add(float x) {
    const int m = __builtin_amdgcn_update_dpp(
        0, __float_as_int(x), CTRL, ROWM, 0xf, false);
    return x + __int_as_float(m);
}

// full 64-lane sum; total lands in lane 63; pure VALU
__device__ __forceinline__ float wave_sum(float x) {
    x = dpp_add<0x111, 0xf>(x);   // row_shr:1
    x = dpp_add<0x112, 0xf>(x);   // row_shr:2
    x = dpp_add<0x114, 0xf>(x);   // row_shr:4
    x = dpp_add<0x118, 0xf>(x);   // row_shr:8
    x = dpp_add<0x142, 0xa>(x);   // row_bcast:15
    x = dpp_add<0x143, 0xc>(x);   // row_bcast:31 -> lane63 total
    return x;
}

__device__ __forceinline__ void load_vecs(const float* __restrict__ x,
                                          size_t base, float (&v)[NV][E]) {
    const size_t strideN = (size_t)MC * DIM;
#pragma unroll
    for (int n = 0; n < NV; ++n) {
        const f32x4 f = *reinterpret_cast<const f32x4*>(x + n * strideN + base);
        v[n][0] = f.x; v[n][1] = f.y; v[n][2] = f.z; v[n][3] = f.w;
    }
}

// Process cur (Gram -> chol -> fwd-subst -> store); optionally prefetch nxt first.
template <bool PREFETCH>
__device__ __forceinline__ void step(const float* __restrict__ x,
                                     float* __restrict__ out,
                                     float (&cur)[NV][E], float (&nxt)[NV][E],
                                     size_t cur_base, size_t nxt_base,
                                     float (*red)[36], int lane, int wave) {
    if (PREFETCH) load_vecs(x, nxt_base, nxt);   // in flight under everything below

    // 36 Gram partials
    float g[36];
#pragma unroll
    for (int i = 0; i < NV; ++i)
#pragma unroll
        for (int j = 0; j <= i; ++j) {
            float s = 0.0f;
#pragma unroll
            for (int e = 0; e < E; ++e) s += cur[i][e] * cur[j][e];
            g[IDX(i, j)] = s;
        }

    // wave-level reduce on the VALU pipe
#pragma unroll
    for (int k = 0; k < 36; ++k) g[k] = wave_sum(g[k]);

    __syncthreads();                 // previous iteration's red reads done
    if (lane == 63) {
#pragma unroll
        for (int k = 0; k < 36; ++k) red[wave][k] = g[k];
    }
    __syncthreads();
#pragma unroll
    for (int k = 0; k < 36; ++k)
        g[k] = red[0][k] + red[1][k] + red[2][k] + red[3][k];   // broadcast reads

    // in-register 8x8 Cholesky (uniform across threads)
    float rdiag[NV];
#pragma unroll
    for (int i = 0; i < NV; ++i) {
#pragma unroll
        for (int j = 0; j < i; ++j) {
            float s = g[IDX(i, j)];
#pragma unroll
            for (int p = 0; p < NV; ++p) {
                if (p >= j) break;
                s -= g[IDX(i, p)] * g[IDX(j, p)];
            }
            g[IDX(i, j)] = s * rdiag[j];
        }
        float d = g[IDX(i, i)];
#pragma unroll
        for (int p = 0; p < NV; ++p) {
            if (p >= i) break;
            d -= g[IDX(i, p)] * g[IDX(i, p)];
        }
        g[IDX(i, i)] = (d > 0.0f) ? sqrtf(d) : 0.0f;
        rdiag[i]     = (d > 0.0f) ? rsqrtf(d) : 0.0f;
    }

    // forward substitution + normalize
#pragma unroll
    for (int i = 0; i < NV; ++i) {
#pragma unroll
        for (int j = 0; j < NV; ++j) {
            if (j >= i) break;
            const float lij = g[IDX(i, j)];
#pragma unroll
            for (int e = 0; e < E; ++e) cur[i][e] -= lij * cur[j][e];
        }
        const float r = rdiag[i];
#pragma unroll
        for (int e = 0; e < E; ++e) cur[i][e] *= r;
    }

    // non-temporal store (output never re-read; keep input L3-resident)
    const size_t strideN = (size_t)MC * DIM;
#pragma unroll
    for (int n = 0; n < NV; ++n) {
        f32x4 f; f.x = cur[n][0]; f.y = cur[n][1]; f.z = cur[n][2]; f.w = cur[n][3];
        __builtin_nontemporal_store(
            f, reinterpret_cast<f32x4*>(out + n * strideN + cur_base));
    }
}

__global__ __launch_bounds__(TPB, 4) void gs_kernel(const float* __restrict__ x,
                                                    float* __restrict__ out) {
    const int t    = threadIdx.x;
    const int lane = t & 63;
    const int wave = t >> 6;

    __shared__ float red[4][36];

    // mc for iteration k: blockIdx.x + k*NBLK  (consecutive blocks -> adjacent mc)
    const size_t b0 = (size_t)(blockIdx.x + 0 * NBLK) * DIM + (size_t)t * 4;
    const size_t b1 = (size_t)(blockIdx.x + 1 * NBLK) * DIM + (size_t)t * 4;
    const size_t b2 = (size_t)(blockIdx.x + 2 * NBLK) * DIM + (size_t)t * 4;
    const size_t b3 = (size_t)(blockIdx.x + 3 * NBLK) * DIM + (size_t)t * 4;

    float A[NV][E], B[NV][E];
    load_vecs(x, b0, A);
    step<true >(x, out, A, B, b0, b1, red, lane, wave);
    step<true >(x, out, B, A, b1, b2, red, lane, wave);
    step<true >(x, out, A, B, b2, b3, red, lane, wave);
    step<false>(x, out, B, A, b3, b3, red, lane, wave);
}

extern "C" void kernel_launch(void* const* d_in, const int* in_sizes, int n_in,
                              void* d_out, int out_size, void* d_ws, size_t ws_size,
                              hipStream_t stream) {
    const float* x = (const float*)d_in[0];
    float* out = (float*)d_out;
    gs_kernel<<<NBLK, TPB, 0, stream>>>(x, out);
}